// Round 1
// baseline (610.605 us; speedup 1.0000x reference)
//
#include <hip/hip_runtime.h>

#define D 64
#define EDIM 16

// ---------------------------------------------------------------------------
// Edge kernel: one wave per edge (grid-stride over edges).
//   e    = edge_attr[i] @ W_edge + b_edge          (16 -> 64)
//   msg  = relu(x[src] + e)
//   aggr[dst] += msg  (atomicAdd, f32, device scope)
// Lane j owns output column j. W_edge column j lives in 16 VGPRs.
// ---------------------------------------------------------------------------
__global__ __launch_bounds__(256) void egin_edge_kernel(
    const float* __restrict__ x,
    const int*   __restrict__ src,
    const int*   __restrict__ dst,
    const float* __restrict__ edge_attr,
    const float* __restrict__ W_edge,
    const float* __restrict__ b_edge,
    float*       __restrict__ aggr,
    int E)
{
    const int lane   = threadIdx.x & 63;
    const int wave   = blockIdx.x * (blockDim.x >> 6) + (threadIdx.x >> 6);
    const int nwaves = gridDim.x * (blockDim.x >> 6);

    // Preload W_edge column `lane` (16 floats) + bias
    float we[EDIM];
#pragma unroll
    for (int k = 0; k < EDIM; ++k) we[k] = W_edge[k * D + lane];
    const float be = b_edge[lane];

    for (int i = wave; i < E; i += nwaves) {
        const int s = src[i];
        const int d = dst[i];

        // 16 edge features: 4x float4, same address across lanes -> broadcast
        const float4* eap = (const float4*)(edge_attr + (size_t)i * EDIM);
        float acc = be;
#pragma unroll
        for (int c = 0; c < 4; ++c) {
            const float4 ea = eap[c];
            acc = fmaf(ea.x, we[4 * c + 0], acc);
            acc = fmaf(ea.y, we[4 * c + 1], acc);
            acc = fmaf(ea.z, we[4 * c + 2], acc);
            acc = fmaf(ea.w, we[4 * c + 3], acc);
        }

        float m = x[(size_t)s * D + lane] + acc;   // coalesced gather row
        m = fmaxf(m, 0.0f);
        atomicAdd(&aggr[(size_t)d * D + lane], m);
    }
}

// ---------------------------------------------------------------------------
// Node kernel: one wave per node (4 nodes per 256-thread block).
//   h = x + aggr ; t = relu(h @ W1 + b1) ; out = t @ W2 + b2
// Lane j owns output column j; W1/W2 column j in 64+64 VGPRs.
// h and t are broadcast across lanes through per-wave LDS rows.
// NOTE: `inout` serves as BOTH aggr (read) and out (write) — row n is fully
// read before row n is written, and each node is visited exactly once.
// ---------------------------------------------------------------------------
__global__ __launch_bounds__(256) void egin_node_kernel(
    const float* __restrict__ x,
    const float* __restrict__ W1,
    const float* __restrict__ b1,
    const float* __restrict__ W2,
    const float* __restrict__ b2,
    float* inout,   // aggr in, final out — intentionally NOT restrict
    int N)
{
    __shared__ float hbuf[4][D];
    __shared__ float tbuf[4][D];

    const int lane = threadIdx.x & 63;
    const int wv   = threadIdx.x >> 6;

    float w1r[D], w2r[D];
#pragma unroll
    for (int k = 0; k < D; ++k) w1r[k] = W1[k * D + lane];
#pragma unroll
    for (int k = 0; k < D; ++k) w2r[k] = W2[k * D + lane];
    const float b1v = b1[lane];
    const float b2v = b2[lane];

    // N == 100000 is divisible by 4, so every wave in an iterating block has
    // a valid node -> __syncthreads() is uniformly executed.
    for (int base = blockIdx.x * 4; base < N; base += gridDim.x * 4) {
        const int    node = base + wv;
        const size_t off  = (size_t)node * D + lane;

        const float h = x[off] + inout[off];
        hbuf[wv][lane] = h;
        __syncthreads();

        float acc = b1v;
#pragma unroll
        for (int k = 0; k < D; k += 4) {
            const float4 hv = *(const float4*)(&hbuf[wv][k]);
            acc = fmaf(hv.x, w1r[k + 0], acc);
            acc = fmaf(hv.y, w1r[k + 1], acc);
            acc = fmaf(hv.z, w1r[k + 2], acc);
            acc = fmaf(hv.w, w1r[k + 3], acc);
        }
        const float t = fmaxf(acc, 0.0f);
        tbuf[wv][lane] = t;
        __syncthreads();

        float acc2 = b2v;
#pragma unroll
        for (int k = 0; k < D; k += 4) {
            const float4 tv = *(const float4*)(&tbuf[wv][k]);
            acc2 = fmaf(tv.x, w2r[k + 0], acc2);
            acc2 = fmaf(tv.y, w2r[k + 1], acc2);
            acc2 = fmaf(tv.z, w2r[k + 2], acc2);
            acc2 = fmaf(tv.w, w2r[k + 3], acc2);
        }
        inout[off] = acc2;
    }
}

// ---------------------------------------------------------------------------
// Inputs (setup_inputs order):
//   0: x         [100000,64] f32
//   1: edge_index[2,E]       int (src = first E, dst = next E)
//   2: edge_attr [E,16]      f32
//   3: W_edge    [16,64]     f32
//   4: b_edge    [64]        f32
//   5: W1        [64,64]     f32
//   6: b1        [64]        f32
//   7: W2        [64,64]     f32
//   8: b2        [64]        f32
// Output: [100000,64] f32
// ---------------------------------------------------------------------------
extern "C" void kernel_launch(void* const* d_in, const int* in_sizes, int n_in,
                              void* d_out, int out_size, void* d_ws, size_t ws_size,
                              hipStream_t stream)
{
    const float* x      = (const float*)d_in[0];
    const int*   eidx   = (const int*)d_in[1];
    const float* eattr  = (const float*)d_in[2];
    const float* W_edge = (const float*)d_in[3];
    const float* b_edge = (const float*)d_in[4];
    const float* W1     = (const float*)d_in[5];
    const float* b1     = (const float*)d_in[6];
    const float* W2     = (const float*)d_in[7];
    const float* b2     = (const float*)d_in[8];
    float*       out    = (float*)d_out;

    const int E = in_sizes[1] / 2;      // 1,600,000
    const int N = in_sizes[0] / D;      // 100,000

    const int* src = eidx;
    const int* dst = eidx + E;

    // Use d_out itself as the aggregation buffer (zero-init first).
    hipMemsetAsync(out, 0, (size_t)N * D * sizeof(float), stream);

    // Edge phase: 2048 blocks x 256 = 8192 waves (full device occupancy).
    egin_edge_kernel<<<2048, 256, 0, stream>>>(x, src, dst, eattr, W_edge,
                                               b_edge, out, E);

    // Node phase.
    egin_node_kernel<<<1024, 256, 0, stream>>>(x, W1, b1, W2, b2, out, N);
}